// Round 4
// baseline (27.300 us; speedup 1.0000x reference)
//
#include <hip/hip_runtime.h>

#define B_SZ 8
#define P_SZ 24
#define H_SZ 448
#define W_SZ 448
#define NUM_CLS 19
#define W4 (W_SZ / 4)                 // 112 float4 per row
#define CH4 (H_SZ * W_SZ / 4)        // 50176 float4 per channel
#define THREADS 256
#define F4_PER_THREAD 4
#define CHUNK4 (THREADS * F4_PER_THREAD)       // 1024 float4 per block
#define BLOCKS_PER_CH (CH4 / CHUNK4)           // 49 (exact)

typedef float f32x4 __attribute__((ext_vector_type(4)));

__global__ __launch_bounds__(THREADS) void fused_distmap_kernel(
        const float* __restrict__ coords, f32x4* __restrict__ out) {
    int ch = blockIdx.x / BLOCKS_PER_CH;       // b * NUM_CLS + cls
    int chunk = blockIdx.x % BLOCKS_PER_CH;
    int b = ch / NUM_CLS;
    int cls = ch % NUM_CLS;

    __shared__ float s_r[P_SZ];
    __shared__ float s_c[P_SZ];
    __shared__ int s_cnt;
    if (threadIdx.x == 0) s_cnt = 0;
    __syncthreads();
    if (threadIdx.x < P_SZ) {
        const float* c = coords + ((size_t)b * P_SZ + threadIdx.x) * 3;
        float rf = c[0], cf = c[1];
        int pcls = (int)c[2];
        // valid = max(r,c) >= 0 ; only points of this channel's class matter
        if (pcls == cls && fmaxf(rf, cf) >= 0.0f) {
            int slot = atomicAdd(&s_cnt, 1);
            s_r[slot] = rf;
            s_c[slot] = cf;
        }
    }
    __syncthreads();
    int cnt = s_cnt;

    size_t chbase = (size_t)ch * CH4;
    int idx0 = chunk * CHUNK4 + threadIdx.x;   // first in-channel float4 index

    if (cnt == 0) {
        f32x4 z = (f32x4)(0.f);
        #pragma unroll
        for (int u = 0; u < F4_PER_THREAD; ++u)
            __builtin_nontemporal_store(z, &out[chbase + idx0 + u * THREADS]);
        return;
    }

    #pragma unroll
    for (int u = 0; u < F4_PER_THREAD; ++u) {
        int idx4 = idx0 + u * THREADS;
        float y  = (float)(idx4 / W4);
        float x0 = (float)((idx4 % W4) * 4);
        f32x4 v = (f32x4)(0.f);
        for (int p = 0; p < cnt; ++p) {
            float dr  = y - s_r[p];
            float dr2 = dr * dr;
            float dc  = x0 - s_c[p];
            if (dr2 + dc * dc                   <= 25.f) v.x = 255.f;
            if (dr2 + (dc+1.f) * (dc+1.f)       <= 25.f) v.y = 255.f;
            if (dr2 + (dc+2.f) * (dc+2.f)       <= 25.f) v.z = 255.f;
            if (dr2 + (dc+3.f) * (dc+3.f)       <= 25.f) v.w = 255.f;
        }
        __builtin_nontemporal_store(v, &out[chbase + idx4]);
    }
}

extern "C" void kernel_launch(void* const* d_in, const int* in_sizes, int n_in,
                              void* d_out, int out_size, void* d_ws, size_t ws_size,
                              hipStream_t stream) {
    const float* coords = (const float*)d_in[1];   // (B, P, 3) f32
    f32x4* out = (f32x4*)d_out;                    // (B, NUM_CLS, H, W) f32

    int grid = B_SZ * NUM_CLS * BLOCKS_PER_CH;     // 7448
    fused_distmap_kernel<<<grid, THREADS, 0, stream>>>(coords, out);
}

// Round 5
// 22.105 us; speedup vs baseline: 1.2350x; 1.2350x over previous
//
#include <hip/hip_runtime.h>

#define B_SZ 8
#define P_SZ 24
#define H_SZ 448
#define W_SZ 448
#define NUM_CLS 19
#define W4 (W_SZ / 4)                 // 112 float4 per row
#define CH4 (H_SZ * W_SZ / 4)        // 50176 float4 per channel
#define THREADS 256
#define F4_PER_THREAD 4
#define CHUNK4 (THREADS * F4_PER_THREAD)       // 1024 float4 per block
#define BLOCKS_PER_CH (CH4 / CHUNK4)           // 49 (exact)

__global__ __launch_bounds__(THREADS) void fused_distmap_kernel(
        const float* __restrict__ coords, float4* __restrict__ out) {
    int ch = blockIdx.x / BLOCKS_PER_CH;       // b * NUM_CLS + cls
    int chunk = blockIdx.x % BLOCKS_PER_CH;
    int b = ch / NUM_CLS;
    int cls = ch % NUM_CLS;

    __shared__ float s_r[P_SZ];
    __shared__ float s_c[P_SZ];
    __shared__ int s_cnt;
    if (threadIdx.x == 0) s_cnt = 0;
    __syncthreads();
    if (threadIdx.x < P_SZ) {
        const float* c = coords + ((size_t)b * P_SZ + threadIdx.x) * 3;
        float rf = c[0], cf = c[1];
        int pcls = (int)c[2];
        // valid = max(r,c) >= 0 ; only points of this channel's class matter
        if (pcls == cls && fmaxf(rf, cf) >= 0.0f) {
            int slot = atomicAdd(&s_cnt, 1);
            s_r[slot] = rf;
            s_c[slot] = cf;
        }
    }
    __syncthreads();
    int cnt = s_cnt;

    size_t chbase = (size_t)ch * CH4;
    int idx0 = chunk * CHUNK4 + threadIdx.x;   // first in-channel float4 index

    if (cnt == 0) {
        float4 z = make_float4(0.f, 0.f, 0.f, 0.f);
        #pragma unroll
        for (int u = 0; u < F4_PER_THREAD; ++u)
            out[chbase + idx0 + u * THREADS] = z;
        return;
    }

    #pragma unroll
    for (int u = 0; u < F4_PER_THREAD; ++u) {
        int idx4 = idx0 + u * THREADS;
        float y  = (float)(idx4 / W4);
        float x0 = (float)((idx4 % W4) * 4);
        float4 v = make_float4(0.f, 0.f, 0.f, 0.f);
        for (int p = 0; p < cnt; ++p) {
            float dr  = y - s_r[p];
            float dr2 = dr * dr;
            float dc  = x0 - s_c[p];
            if (dr2 + dc * dc                   <= 25.f) v.x = 255.f;
            if (dr2 + (dc+1.f) * (dc+1.f)       <= 25.f) v.y = 255.f;
            if (dr2 + (dc+2.f) * (dc+2.f)       <= 25.f) v.z = 255.f;
            if (dr2 + (dc+3.f) * (dc+3.f)       <= 25.f) v.w = 255.f;
        }
        out[chbase + idx4] = v;
    }
}

extern "C" void kernel_launch(void* const* d_in, const int* in_sizes, int n_in,
                              void* d_out, int out_size, void* d_ws, size_t ws_size,
                              hipStream_t stream) {
    const float* coords = (const float*)d_in[1];   // (B, P, 3) f32
    float4* out = (float4*)d_out;                  // (B, NUM_CLS, H, W) f32

    int grid = B_SZ * NUM_CLS * BLOCKS_PER_CH;     // 7448
    fused_distmap_kernel<<<grid, THREADS, 0, stream>>>(coords, out);
}